// Round 1
// baseline (448.172 us; speedup 1.0000x reference)
//
#include <hip/hip_runtime.h>

#define SCAN_BS 1024

// ---------------- CSR build ----------------

__global__ void k_edge_count(const int* __restrict__ dst, int E, int* __restrict__ deg) {
    int e = blockIdx.x * blockDim.x + threadIdx.x;
    if (e < E) atomicAdd(&deg[dst[e]], 1);
}

__global__ void k_norm(const int* __restrict__ deg, float* __restrict__ norm, int N) {
    int i = blockIdx.x * blockDim.x + threadIdx.x;
    if (i < N) norm[i] = rsqrtf((float)(deg[i] + 1));
}

__global__ void k_scan_partial(const int* __restrict__ deg, int N, int* __restrict__ partial) {
    __shared__ int lds[SCAN_BS];
    int t = threadIdx.x;
    int i = blockIdx.x * SCAN_BS + t;
    lds[t] = (i < N) ? deg[i] : 0;
    __syncthreads();
    for (int s = SCAN_BS / 2; s > 0; s >>= 1) {
        if (t < s) lds[t] += lds[t + s];
        __syncthreads();
    }
    if (t == 0) partial[blockIdx.x] = lds[0];
}

__global__ void k_scan_exclusive(int* __restrict__ partial, int nb) {
    if (threadIdx.x == 0 && blockIdx.x == 0) {
        int run = 0;
        for (int b = 0; b < nb; ++b) { int v = partial[b]; partial[b] = run; run += v; }
    }
}

__global__ void k_scan_final(const int* __restrict__ deg, int N, const int* __restrict__ partial,
                             int* __restrict__ offs, int* __restrict__ cursor, int E) {
    __shared__ int lds[SCAN_BS];
    int t = threadIdx.x;
    int i = blockIdx.x * SCAN_BS + t;
    int v = (i < N) ? deg[i] : 0;
    lds[t] = v;
    __syncthreads();
    for (int s = 1; s < SCAN_BS; s <<= 1) {
        int add = (t >= s) ? lds[t - s] : 0;
        __syncthreads();
        lds[t] += add;
        __syncthreads();
    }
    if (i < N) {
        int excl = partial[blockIdx.x] + lds[t] - v;
        offs[i] = excl;
        cursor[i] = excl;
    }
    if (i == 0) offs[N] = E;
}

__global__ void k_fill(const int* __restrict__ src, const int* __restrict__ dst, int E,
                       int* __restrict__ cursor, int* __restrict__ csr) {
    int e = blockIdx.x * blockDim.x + threadIdx.x;
    if (e < E) {
        int pos = atomicAdd(&cursor[dst[e]], 1);
        csr[pos] = src[e];
    }
}

// ---------------- hops (work in hs = norm*h space) ----------------

__global__ void k_prep(const float4* __restrict__ x, const float* __restrict__ norm,
                       float4* __restrict__ out, int N) {
    int t = blockIdx.x * blockDim.x + threadIdx.x; // one float4 (8 per node)
    int i = t >> 3;
    if (i < N) {
        float n = norm[i];
        float4 v = x[t];
        v.x *= n; v.y *= n; v.z *= n; v.w *= n;
        out[t] = v;
    }
}

// hs_out[i] = norm[i]^2 * (sum_{src in in(i)} hs_in[src] + hs_in[i])   (intermediate)
// h_out[i]  = norm[i]   * (sum ... + hs_in[i])                          (last hop)
template <bool LAST>
__global__ void k_hop(const float* __restrict__ hin, const float* __restrict__ norm,
                      const int* __restrict__ offs, const int* __restrict__ csr,
                      float* __restrict__ hout, int N) {
    int group = (blockIdx.x * blockDim.x + threadIdx.x) >> 3;
    int l = threadIdx.x & 7;
    if (group >= N) return;
    const float4* hin4 = (const float4*)hin;
    int beg = offs[group], end = offs[group + 1];
    float4 acc = hin4[group * 8 + l]; // self-loop term
    int k = beg;
    // full chunks of 8: batch loads for MLP
    for (; k + 8 <= end; k += 8) {
        int e = csr[k + l];
        float4 v[8];
#pragma unroll
        for (int j = 0; j < 8; ++j) {
            int s = __shfl(e, j, 8);
            v[j] = hin4[s * 8 + l];
        }
#pragma unroll
        for (int j = 0; j < 8; ++j) {
            acc.x += v[j].x; acc.y += v[j].y; acc.z += v[j].z; acc.w += v[j].w;
        }
    }
    if (k < end) {
        int e = csr[min(k + l, end - 1)];
        int m = end - k;
        for (int j = 0; j < m; ++j) {
            int s = __shfl(e, j, 8);
            float4 v = hin4[s * 8 + l];
            acc.x += v.x; acc.y += v.y; acc.z += v.z; acc.w += v.w;
        }
    }
    float ni = norm[group];
    float sc = LAST ? ni : ni * ni;
    acc.x *= sc; acc.y *= sc; acc.z *= sc; acc.w *= sc;
    ((float4*)hout)[group * 8 + l] = acc;
}

// ---------------- GCN linear + mean-pool + classifier, one block per graph ----------------

__global__ __launch_bounds__(256) void k_gcn_pool(
        const float* __restrict__ h, const int* __restrict__ batch, int N,
        const float* __restrict__ gw, const float* __restrict__ gb,
        const float* __restrict__ w1, const float* __restrict__ b1,
        const float* __restrict__ w2, const float* __restrict__ b2,
        float* __restrict__ out) {
    __shared__ float wT[32][64];   // wT[k][c] = gw[c*32+k] (transposed, conflict-free reads)
    __shared__ float gbs[64];
    __shared__ float rows[4][32];
    __shared__ float part[4][64];
    __shared__ float havg[64];
    __shared__ float h1s[32];
    __shared__ int se[2];
    int t = threadIdx.x;
    int g = blockIdx.x;
    for (int idx = t; idx < 64 * 32; idx += 256) {
        int c = idx >> 5, k = idx & 31;
        wT[k][c] = gw[idx];
    }
    if (t < 64) gbs[t] = gb[t];
    if (t < 2) { // lower_bound(batch, g) and lower_bound(batch, g+1)
        int target = g + t;
        int lo = 0, hi = N;
        while (lo < hi) { int mid = (lo + hi) >> 1; if (batch[mid] < target) lo = mid + 1; else hi = mid; }
        se[t] = lo;
    }
    __syncthreads();
    int start = se[0], end = se[1];
    int c = t & 63, nl = t >> 6; // feature, node-lane (4 nodes per iter)
    float acc = 0.f;
    for (int n0 = start; n0 < end; n0 += 4) {
        if (t < 128) {
            int nn = n0 + (t >> 5);
            rows[t >> 5][t & 31] = (nn < end) ? h[nn * 32 + (t & 31)] : 0.f;
        }
        __syncthreads();
        if (n0 + nl < end) {
            float d = gbs[c];
#pragma unroll
            for (int k = 0; k < 32; ++k) d += rows[nl][k] * wT[k][c];
            acc += fmaxf(d, 0.f);
        }
        __syncthreads();
    }
    part[nl][c] = acc;
    __syncthreads();
    if (t < 64) {
        float s = part[0][t] + part[1][t] + part[2][t] + part[3][t];
        int cnt = end - start;
        havg[t] = s / (float)(cnt > 0 ? cnt : 1);
    }
    __syncthreads();
    if (t < 32) {
        float d = b1[t];
#pragma unroll
        for (int k = 0; k < 64; ++k) d += havg[k] * w1[t * 64 + k];
        h1s[t] = fmaxf(d, 0.f);
    }
    __syncthreads();
    if (t < 16) {
        float d = b2[t];
#pragma unroll
        for (int j = 0; j < 32; ++j) d += h1s[j] * w2[t * 32 + j];
        out[g * 16 + t] = d;
    }
}

// ---------------- launch ----------------

extern "C" void kernel_launch(void* const* d_in, const int* in_sizes, int n_in,
                              void* d_out, int out_size, void* d_ws, size_t ws_size,
                              hipStream_t stream) {
    const float* x     = (const float*)d_in[0];
    const int*   ei    = (const int*)d_in[1];
    const int*   batch = (const int*)d_in[2];
    const float* gw    = (const float*)d_in[3];
    const float* gb    = (const float*)d_in[4];
    const float* w1    = (const float*)d_in[5];
    const float* b1    = (const float*)d_in[6];
    const float* w2    = (const float*)d_in[7];
    const float* b2    = (const float*)d_in[8];
    float* out = (float*)d_out;

    int N = in_sizes[2];
    int E = in_sizes[1] / 2;
    int G = out_size / 16;
    const int* srcp = ei;
    const int* dstp = ei + E;

    char* ws = (char*)d_ws;
    size_t off = 0;
    auto alloc = [&](size_t bytes) -> void* {
        void* p = ws + off;
        off += (bytes + 255) & ~(size_t)255;
        return p;
    };
    int*   deg     = (int*)alloc((size_t)N * 4);
    int*   offs    = (int*)alloc((size_t)(N + 1) * 4);
    int*   cursor  = (int*)alloc((size_t)N * 4);
    int*   partial = (int*)alloc(1024 * 4);
    int*   csr     = (int*)alloc((size_t)E * 4);
    float* norm    = (float*)alloc((size_t)N * 4);
    float* bufA    = (float*)alloc((size_t)N * 32 * 4);
    float* bufB    = (float*)alloc((size_t)N * 32 * 4);

    hipMemsetAsync(deg, 0, (size_t)N * 4, stream);

    int eb = (E + 255) / 256;
    int nb = (N + SCAN_BS - 1) / SCAN_BS;
    int pb = (N * 8 + 255) / 256; // one float4 slice per thread

    k_edge_count<<<eb, 256, 0, stream>>>(dstp, E, deg);
    k_norm<<<(N + 255) / 256, 256, 0, stream>>>(deg, norm, N);
    k_scan_partial<<<nb, SCAN_BS, 0, stream>>>(deg, N, partial);
    k_scan_exclusive<<<1, 64, 0, stream>>>(partial, nb);
    k_scan_final<<<nb, SCAN_BS, 0, stream>>>(deg, N, partial, offs, cursor, E);
    k_fill<<<eb, 256, 0, stream>>>(srcp, dstp, E, cursor, csr);

    k_prep<<<pb, 256, 0, stream>>>((const float4*)x, norm, (float4*)bufA, N);
    k_hop<false><<<pb, 256, 0, stream>>>(bufA, norm, offs, csr, bufB, N);
    k_hop<false><<<pb, 256, 0, stream>>>(bufB, norm, offs, csr, bufA, N);
    k_hop<true ><<<pb, 256, 0, stream>>>(bufA, norm, offs, csr, bufB, N);

    k_gcn_pool<<<G, 256, 0, stream>>>(bufB, batch, N, gw, gb, w1, b1, w2, b2, out);
}

// Round 2
// 409.046 us; speedup vs baseline: 1.0957x; 1.0957x over previous
//
#include <hip/hip_runtime.h>

#define SCAN_BS 1024

// ---------------- CSR build ----------------

__global__ void k_edge_count(const int* __restrict__ dst, int E, int* __restrict__ deg) {
    int e = blockIdx.x * blockDim.x + threadIdx.x;
    if (e < E) atomicAdd(&deg[dst[e]], 1);
}

__global__ void k_norm(const int* __restrict__ deg, float* __restrict__ norm, int N) {
    int i = blockIdx.x * blockDim.x + threadIdx.x;
    if (i < N) norm[i] = rsqrtf((float)(deg[i] + 1));
}

__global__ void k_scan_partial(const int* __restrict__ deg, int N, int* __restrict__ partial) {
    __shared__ int lds[SCAN_BS];
    int t = threadIdx.x;
    int i = blockIdx.x * SCAN_BS + t;
    lds[t] = (i < N) ? deg[i] : 0;
    __syncthreads();
    for (int s = SCAN_BS / 2; s > 0; s >>= 1) {
        if (t < s) lds[t] += lds[t + s];
        __syncthreads();
    }
    if (t == 0) partial[blockIdx.x] = lds[0];
}

__global__ void k_scan_exclusive(int* __restrict__ partial, int nb) {
    if (threadIdx.x == 0 && blockIdx.x == 0) {
        int run = 0;
        for (int b = 0; b < nb; ++b) { int v = partial[b]; partial[b] = run; run += v; }
    }
}

__global__ void k_scan_final(const int* __restrict__ deg, int N, const int* __restrict__ partial,
                             int* __restrict__ offs, int* __restrict__ cursor, int E) {
    __shared__ int lds[SCAN_BS];
    int t = threadIdx.x;
    int i = blockIdx.x * SCAN_BS + t;
    int v = (i < N) ? deg[i] : 0;
    lds[t] = v;
    __syncthreads();
    for (int s = 1; s < SCAN_BS; s <<= 1) {
        int add = (t >= s) ? lds[t - s] : 0;
        __syncthreads();
        lds[t] += add;
        __syncthreads();
    }
    if (i < N) {
        int excl = partial[blockIdx.x] + lds[t] - v;
        offs[i] = excl;
        cursor[i] = excl;
    }
    if (i == 0) offs[N] = E;
}

// Multi-pass windowed CSR fill: pass p only fills dst in [p*N/P,(p+1)*N/P).
// Shrinks the random-write working set to ~1.6 MB (L2-resident per XCD),
// killing the 16x HBM write amplification of the single-pass scatter.
// Passes write disjoint regions -> no inter-pass sync needed.
__global__ void k_fill(const int* __restrict__ src, const int* __restrict__ dst, int E,
                       int* __restrict__ cursor, int* __restrict__ csr, int N) {
    const int P = 4;
    int stride = gridDim.x * blockDim.x;
    int base = blockIdx.x * blockDim.x + threadIdx.x;
#pragma unroll
    for (int p = 0; p < P; ++p) {
        int lo = (int)((long long)N * p / P);
        int hi = (int)((long long)N * (p + 1) / P);
        for (int e = base; e < E; e += stride) {
            int d = dst[e];
            if (d >= lo && d < hi) {
                int pos = atomicAdd(&cursor[d], 1);
                csr[pos] = src[e];
            }
        }
    }
}

// ---------------- hops (work in hs = norm*h space) ----------------

__global__ void k_prep(const float4* __restrict__ x, const float* __restrict__ norm,
                       float4* __restrict__ out, int N) {
    int t = blockIdx.x * blockDim.x + threadIdx.x; // one float4 (8 per node)
    int i = t >> 3;
    if (i < N) {
        float n = norm[i];
        float4 v = x[t];
        v.x *= n; v.y *= n; v.z *= n; v.w *= n;
        out[t] = v;
    }
}

// hs_out[i] = norm[i]^2 * (sum_{src in in(i)} hs_in[src] + hs_in[i])   (intermediate)
// h_out[i]  = norm[i]   * (sum ... + hs_in[i])                          (last hop)
template <bool LAST>
__global__ void k_hop(const float* __restrict__ hin, const float* __restrict__ norm,
                      const int* __restrict__ offs, const int* __restrict__ csr,
                      float* __restrict__ hout, int N) {
    int group = (blockIdx.x * blockDim.x + threadIdx.x) >> 3;
    int l = threadIdx.x & 7;
    if (group >= N) return;
    const float4* hin4 = (const float4*)hin;
    int beg = offs[group], end = offs[group + 1];
    float4 acc = hin4[group * 8 + l]; // self-loop term
    int k = beg;
    // full chunks of 8: batch loads for MLP
    for (; k + 8 <= end; k += 8) {
        int e = csr[k + l];
        float4 v[8];
#pragma unroll
        for (int j = 0; j < 8; ++j) {
            int s = __shfl(e, j, 8);
            v[j] = hin4[s * 8 + l];
        }
#pragma unroll
        for (int j = 0; j < 8; ++j) {
            acc.x += v[j].x; acc.y += v[j].y; acc.z += v[j].z; acc.w += v[j].w;
        }
    }
    if (k < end) {
        int e = csr[min(k + l, end - 1)];
        int m = end - k;
        for (int j = 0; j < m; ++j) {
            int s = __shfl(e, j, 8);
            float4 v = hin4[s * 8 + l];
            acc.x += v.x; acc.y += v.y; acc.z += v.z; acc.w += v.w;
        }
    }
    float ni = norm[group];
    float sc = LAST ? ni : ni * ni;
    acc.x *= sc; acc.y *= sc; acc.z *= sc; acc.w *= sc;
    ((float4*)hout)[group * 8 + l] = acc;
}

// ---------------- GCN linear + mean-pool + classifier, one block per graph ----------------

__global__ __launch_bounds__(256) void k_gcn_pool(
        const float* __restrict__ h, const int* __restrict__ batch, int N,
        const float* __restrict__ gw, const float* __restrict__ gb,
        const float* __restrict__ w1, const float* __restrict__ b1,
        const float* __restrict__ w2, const float* __restrict__ b2,
        float* __restrict__ out) {
    __shared__ float wT[32][64];   // wT[k][c] = gw[c*32+k] (transposed, conflict-free reads)
    __shared__ float gbs[64];
    __shared__ float rows[4][32];
    __shared__ float part[4][64];
    __shared__ float havg[64];
    __shared__ float h1s[32];
    __shared__ int se[2];
    int t = threadIdx.x;
    int g = blockIdx.x;
    for (int idx = t; idx < 64 * 32; idx += 256) {
        int c = idx >> 5, k = idx & 31;
        wT[k][c] = gw[idx];
    }
    if (t < 64) gbs[t] = gb[t];
    if (t < 2) { // lower_bound(batch, g) and lower_bound(batch, g+1)
        int target = g + t;
        int lo = 0, hi = N;
        while (lo < hi) { int mid = (lo + hi) >> 1; if (batch[mid] < target) lo = mid + 1; else hi = mid; }
        se[t] = lo;
    }
    __syncthreads();
    int start = se[0], end = se[1];
    int c = t & 63, nl = t >> 6; // feature, node-lane (4 nodes per iter)
    float acc = 0.f;
    for (int n0 = start; n0 < end; n0 += 4) {
        if (t < 128) {
            int nn = n0 + (t >> 5);
            rows[t >> 5][t & 31] = (nn < end) ? h[nn * 32 + (t & 31)] : 0.f;
        }
        __syncthreads();
        if (n0 + nl < end) {
            float d = gbs[c];
#pragma unroll
            for (int k = 0; k < 32; ++k) d += rows[nl][k] * wT[k][c];
            acc += fmaxf(d, 0.f);
        }
        __syncthreads();
    }
    part[nl][c] = acc;
    __syncthreads();
    if (t < 64) {
        float s = part[0][t] + part[1][t] + part[2][t] + part[3][t];
        int cnt = end - start;
        havg[t] = s / (float)(cnt > 0 ? cnt : 1);
    }
    __syncthreads();
    if (t < 32) {
        float d = b1[t];
#pragma unroll
        for (int k = 0; k < 64; ++k) d += havg[k] * w1[t * 64 + k];
        h1s[t] = fmaxf(d, 0.f);
    }
    __syncthreads();
    if (t < 16) {
        float d = b2[t];
#pragma unroll
        for (int j = 0; j < 32; ++j) d += h1s[j] * w2[t * 32 + j];
        out[g * 16 + t] = d;
    }
}

// ---------------- launch ----------------

extern "C" void kernel_launch(void* const* d_in, const int* in_sizes, int n_in,
                              void* d_out, int out_size, void* d_ws, size_t ws_size,
                              hipStream_t stream) {
    const float* x     = (const float*)d_in[0];
    const int*   ei    = (const int*)d_in[1];
    const int*   batch = (const int*)d_in[2];
    const float* gw    = (const float*)d_in[3];
    const float* gb    = (const float*)d_in[4];
    const float* w1    = (const float*)d_in[5];
    const float* b1    = (const float*)d_in[6];
    const float* w2    = (const float*)d_in[7];
    const float* b2    = (const float*)d_in[8];
    float* out = (float*)d_out;

    int N = in_sizes[2];
    int E = in_sizes[1] / 2;
    int G = out_size / 16;
    const int* srcp = ei;
    const int* dstp = ei + E;

    char* ws = (char*)d_ws;
    size_t off = 0;
    auto alloc = [&](size_t bytes) -> void* {
        void* p = ws + off;
        off += (bytes + 255) & ~(size_t)255;
        return p;
    };
    int*   deg     = (int*)alloc((size_t)N * 4);
    int*   offs    = (int*)alloc((size_t)(N + 1) * 4);
    int*   cursor  = (int*)alloc((size_t)N * 4);
    int*   partial = (int*)alloc(1024 * 4);
    int*   csr     = (int*)alloc((size_t)E * 4);
    float* norm    = (float*)alloc((size_t)N * 4);
    float* bufA    = (float*)alloc((size_t)N * 32 * 4);
    float* bufB    = (float*)alloc((size_t)N * 32 * 4);

    hipMemsetAsync(deg, 0, (size_t)N * 4, stream);

    int eb = (E + 255) / 256;
    int nb = (N + SCAN_BS - 1) / SCAN_BS;
    int pb = (N * 8 + 255) / 256; // one float4 slice per thread

    k_edge_count<<<eb, 256, 0, stream>>>(dstp, E, deg);
    k_norm<<<(N + 255) / 256, 256, 0, stream>>>(deg, norm, N);
    k_scan_partial<<<nb, SCAN_BS, 0, stream>>>(deg, N, partial);
    k_scan_exclusive<<<1, 64, 0, stream>>>(partial, nb);
    k_scan_final<<<nb, SCAN_BS, 0, stream>>>(deg, N, partial, offs, cursor, E);
    // grid-stride fill, 1024 blocks: each block loops P=4 windowed passes
    k_fill<<<1024, 256, 0, stream>>>(srcp, dstp, E, cursor, csr, N);

    k_prep<<<pb, 256, 0, stream>>>((const float4*)x, norm, (float4*)bufA, N);
    k_hop<false><<<pb, 256, 0, stream>>>(bufA, norm, offs, csr, bufB, N);
    k_hop<false><<<pb, 256, 0, stream>>>(bufB, norm, offs, csr, bufA, N);
    k_hop<true ><<<pb, 256, 0, stream>>>(bufA, norm, offs, csr, bufB, N);

    k_gcn_pool<<<G, 256, 0, stream>>>(bufB, batch, N, gw, gb, w1, b1, w2, b2, out);
}